// Round 1
// baseline (1018.921 us; speedup 1.0000x reference)
//
#include <hip/hip_runtime.h>
#include <math.h>

#define IN_DIM 128
#define OUT_DIM 128
#define NHEAD 4
#define HC 32
#define NEG_SLOPE 0.2f
#define LN_EPS 1e-5f
#define SM_EPS 1e-16f

__device__ __forceinline__ unsigned f2key(float f) {
    unsigned b = __float_as_uint(f);
    return (b & 0x80000000u) ? ~b : (b | 0x80000000u);
}
__device__ __forceinline__ float key2f(unsigned k) {
    return (k & 0x80000000u) ? __uint_as_float(k & 0x7fffffffu) : __uint_as_float(~k);
}
__device__ __forceinline__ float leaky(float v) { return v > 0.f ? v : NEG_SLOPE * v; }

// ---------------- K1: h = x @ W  + alpha_src/alpha_dst ----------------
// block = 128 threads (one output column each), 4 nodes per block.
__global__ void k_gemm_alpha(const float* __restrict__ x, const float* __restrict__ W,
                             const float* __restrict__ a_src, const float* __restrict__ a_dst,
                             float* __restrict__ h, float* __restrict__ asrc_out,
                             float* __restrict__ adst_out, int N)
{
    const int NPB = 4;
    int node0 = blockIdx.x * NPB;
    int j = threadIdx.x;                       // output column 0..127
    __shared__ float xs[NPB][IN_DIM];

    for (int idx = threadIdx.x; idx < NPB * IN_DIM; idx += blockDim.x) {
        int ni = idx >> 7, k = idx & 127;
        int node = node0 + ni;
        xs[ni][k] = (node < N) ? x[(size_t)node * IN_DIM + k] : 0.f;
    }
    __syncthreads();

    float acc[NPB] = {0.f, 0.f, 0.f, 0.f};
    for (int k = 0; k < IN_DIM; ++k) {
        float w = W[k * OUT_DIM + j];
        #pragma unroll
        for (int ni = 0; ni < NPB; ++ni) acc[ni] += xs[ni][k] * w;
    }

    int hh = j >> 5;                           // head index
    float as = a_src[hh * HC + (j & 31)];
    float ad = a_dst[hh * HC + (j & 31)];

    #pragma unroll
    for (int ni = 0; ni < NPB; ++ni) {
        int node = node0 + ni;
        if (node >= N) break;                  // uniform across block
        h[(size_t)node * OUT_DIM + j] = acc[ni];
        float s = acc[ni] * as;
        float d = acc[ni] * ad;
        #pragma unroll
        for (int m = 16; m >= 1; m >>= 1) {
            s += __shfl_xor(s, m, 64);
            d += __shfl_xor(d, m, 64);
        }
        if ((j & 31) == 0) {
            asrc_out[node * NHEAD + hh] = s;
            adst_out[node * NHEAD + hh] = d;
        }
    }
}

// ---------------- K3: segment max over destinations ----------------
__global__ void k_edge_max(const int* __restrict__ ei,
                           const float* __restrict__ asrc, const float* __restrict__ adst,
                           unsigned* __restrict__ emax, int E, int N)
{
    int tid = blockIdx.x * blockDim.x + threadIdx.x;
    int total = (E + N) * NHEAD;
    if (tid >= total) return;
    int e = tid >> 2, hh = tid & 3;
    int s, d;
    if (e < E) { s = ei[e]; d = ei[E + e]; } else { s = d = e - E; }
    float v = leaky(asrc[s * NHEAD + hh] + adst[d * NHEAD + hh]);
    atomicMax(&emax[d * NHEAD + hh], f2key(v));
}

// ---------------- K4: segment sum of exp ----------------
__global__ void k_edge_sum(const int* __restrict__ ei,
                           const float* __restrict__ asrc, const float* __restrict__ adst,
                           const unsigned* __restrict__ emax, float* __restrict__ denom,
                           int E, int N)
{
    int tid = blockIdx.x * blockDim.x + threadIdx.x;
    int total = (E + N) * NHEAD;
    if (tid >= total) return;
    int e = tid >> 2, hh = tid & 3;
    int s, d;
    if (e < E) { s = ei[e]; d = ei[E + e]; } else { s = d = e - E; }
    float v = leaky(asrc[s * NHEAD + hh] + adst[d * NHEAD + hh]);
    float ee = expf(v - key2f(emax[d * NHEAD + hh]));
    atomicAdd(&denom[d * NHEAD + hh], ee);
}

// ---------------- K5: scatter messages ----------------
__global__ void k_aggregate(const int* __restrict__ ei, const float* __restrict__ h,
                            const float* __restrict__ asrc, const float* __restrict__ adst,
                            const unsigned* __restrict__ emax, const float* __restrict__ denom,
                            float* __restrict__ out, int E, int N)
{
    int tid = blockIdx.x * blockDim.x + threadIdx.x;
    int total = (E + N) * OUT_DIM;
    if (tid >= total) return;
    int e = tid >> 7, c = tid & 127, hh = c >> 5;
    int s, d;
    if (e < E) { s = ei[e]; d = ei[E + e]; } else { s = d = e - E; }
    float v = leaky(asrc[s * NHEAD + hh] + adst[d * NHEAD + hh]);
    float alpha = expf(v - key2f(emax[d * NHEAD + hh])) / (denom[d * NHEAD + hh] + SM_EPS);
    atomicAdd(&out[(size_t)d * OUT_DIM + c], h[(size_t)s * OUT_DIM + c] * alpha);
}

// ---------------- K6: bias + LayerNorm + ReLU ----------------
// one wave (64 lanes) per node; each lane owns 2 channels.
__global__ void k_ln_relu(float* __restrict__ out, const float* __restrict__ bias,
                          const float* __restrict__ gamma, const float* __restrict__ beta, int N)
{
    int node = blockIdx.x;
    if (node >= N) return;
    int l = threadIdx.x;                  // 0..63
    float2 v = *reinterpret_cast<const float2*>(&out[(size_t)node * OUT_DIM + l * 2]);
    float2 b = *reinterpret_cast<const float2*>(&bias[l * 2]);
    v.x += b.x; v.y += b.y;
    float s = v.x + v.y;
    float ss = v.x * v.x + v.y * v.y;
    #pragma unroll
    for (int m = 32; m >= 1; m >>= 1) {
        s  += __shfl_xor(s, m, 64);
        ss += __shfl_xor(ss, m, 64);
    }
    float mean = s * (1.f / OUT_DIM);
    float var = ss * (1.f / OUT_DIM) - mean * mean;
    float r = rsqrtf(var + LN_EPS);
    float2 g = *reinterpret_cast<const float2*>(&gamma[l * 2]);
    float2 be = *reinterpret_cast<const float2*>(&beta[l * 2]);
    float ox = (v.x - mean) * r * g.x + be.x;
    float oy = (v.y - mean) * r * g.y + be.y;
    ox = ox > 0.f ? ox : 0.f;
    oy = oy > 0.f ? oy : 0.f;
    *reinterpret_cast<float2*>(&out[(size_t)node * OUT_DIM + l * 2]) = make_float2(ox, oy);
}

extern "C" void kernel_launch(void* const* d_in, const int* in_sizes, int n_in,
                              void* d_out, int out_size, void* d_ws, size_t ws_size,
                              hipStream_t stream) {
    const float* x      = (const float*)d_in[0];
    const int*   ei     = (const int*)d_in[1];
    const float* W      = (const float*)d_in[2];
    const float* a_src  = (const float*)d_in[3];
    const float* a_dst  = (const float*)d_in[4];
    const float* bias   = (const float*)d_in[5];
    const float* gamma  = (const float*)d_in[6];
    const float* beta   = (const float*)d_in[7];
    float* out = (float*)d_out;

    const int N = in_sizes[0] / IN_DIM;
    const int E = in_sizes[1] / 2;

    // workspace layout (floats)
    float* h      = (float*)d_ws;                     // N*128
    float* asrc   = h + (size_t)N * OUT_DIM;          // N*4
    float* adst   = asrc + (size_t)N * NHEAD;         // N*4
    unsigned* emax = (unsigned*)(adst + (size_t)N * NHEAD); // N*4
    float* denom  = (float*)(emax + (size_t)N * NHEAD);     // N*4

    // K1: GEMM + alphas
    k_gemm_alpha<<<(N + 3) / 4, 128, 0, stream>>>(x, W, a_src, a_dst, h, asrc, adst, N);

    // K2: init accumulators
    hipMemsetAsync(out, 0, (size_t)N * OUT_DIM * sizeof(float), stream);
    hipMemsetAsync(emax, 0, (size_t)N * NHEAD * sizeof(unsigned), stream);
    hipMemsetAsync(denom, 0, (size_t)N * NHEAD * sizeof(float), stream);

    int tot_eh = (E + N) * NHEAD;
    k_edge_max<<<(tot_eh + 255) / 256, 256, 0, stream>>>(ei, asrc, adst, emax, E, N);
    k_edge_sum<<<(tot_eh + 255) / 256, 256, 0, stream>>>(ei, asrc, adst, emax, denom, E, N);

    int tot_ec = (E + N) * OUT_DIM;
    k_aggregate<<<(tot_ec + 255) / 256, 256, 0, stream>>>(ei, h, asrc, adst, emax, denom, out, E, N);

    k_ln_relu<<<N, 64, 0, stream>>>(out, bias, gamma, beta, N);
}

// Round 2
// 386.415 us; speedup vs baseline: 2.6369x; 2.6369x over previous
//
#include <hip/hip_runtime.h>
#include <hip/hip_bf16.h>
#include <math.h>

#define IN_DIM 128
#define OUT_DIM 128
#define NHEAD 4
#define HC 32
#define NEG_SLOPE 0.2f
#define LN_EPS 1e-5f
#define SM_EPS 1e-16f
#define SCAN_B 256

__device__ __forceinline__ float leaky(float v) { return v > 0.f ? v : NEG_SLOPE * v; }

// ---------------- K1: h = x @ W (bf16 out) + alpha_src/alpha_dst (fp32) ----------------
// block = 128 threads (one output column each), 4 nodes per block.
__global__ void k_gemm_alpha(const float* __restrict__ x, const float* __restrict__ W,
                             const float* __restrict__ a_src, const float* __restrict__ a_dst,
                             __hip_bfloat16* __restrict__ hB, float* __restrict__ asrc_out,
                             float* __restrict__ adst_out, int N)
{
    const int NPB = 4;
    int node0 = blockIdx.x * NPB;
    int j = threadIdx.x;                       // output column 0..127
    __shared__ float xs[NPB][IN_DIM];

    for (int idx = threadIdx.x; idx < NPB * IN_DIM; idx += blockDim.x) {
        int ni = idx >> 7, k = idx & 127;
        int node = node0 + ni;
        xs[ni][k] = (node < N) ? x[(size_t)node * IN_DIM + k] : 0.f;
    }
    __syncthreads();

    float acc[NPB] = {0.f, 0.f, 0.f, 0.f};
    for (int k = 0; k < IN_DIM; ++k) {
        float w = W[k * OUT_DIM + j];
        #pragma unroll
        for (int ni = 0; ni < NPB; ++ni) acc[ni] += xs[ni][k] * w;
    }

    int hh = j >> 5;                           // head index
    float as = a_src[hh * HC + (j & 31)];
    float ad = a_dst[hh * HC + (j & 31)];

    #pragma unroll
    for (int ni = 0; ni < NPB; ++ni) {
        int node = node0 + ni;
        if (node >= N) break;                  // uniform across block
        hB[(size_t)node * OUT_DIM + j] = __float2bfloat16(acc[ni]);
        float s = acc[ni] * as;
        float d = acc[ni] * ad;
        #pragma unroll
        for (int m = 16; m >= 1; m >>= 1) {
            s += __shfl_xor(s, m, 64);
            d += __shfl_xor(d, m, 64);
        }
        if ((j & 31) == 0) {
            asrc_out[node * NHEAD + hh] = s;
            adst_out[node * NHEAD + hh] = d;
        }
    }
}

// ---------------- CSR build ----------------
__global__ void k_count(const int* __restrict__ ei, int* __restrict__ deg, int E, int N)
{
    int e = blockIdx.x * blockDim.x + threadIdx.x;
    if (e >= E + N) return;
    int d = (e < E) ? ei[E + e] : (e - E);
    atomicAdd(&deg[d], 1);
}

__global__ void k_scan1(const int* __restrict__ deg, int* __restrict__ chunk_excl,
                        int* __restrict__ ct, int N)
{
    __shared__ int sm[SCAN_B];
    int i = blockIdx.x * SCAN_B + threadIdx.x;
    int v = (i < N) ? deg[i] : 0;
    sm[threadIdx.x] = v;
    __syncthreads();
    for (int off = 1; off < SCAN_B; off <<= 1) {
        int t = (threadIdx.x >= off) ? sm[threadIdx.x - off] : 0;
        __syncthreads();
        sm[threadIdx.x] += t;
        __syncthreads();
    }
    if (i < N) chunk_excl[i] = sm[threadIdx.x] - v;       // exclusive within chunk
    if (threadIdx.x == SCAN_B - 1) ct[blockIdx.x] = sm[threadIdx.x];
}

__global__ void k_scan2(const int* __restrict__ ct, int* __restrict__ cte, int nchunks)
{
    __shared__ int sm[512];
    int v = (threadIdx.x < nchunks) ? ct[threadIdx.x] : 0;
    sm[threadIdx.x] = v;
    __syncthreads();
    for (int off = 1; off < 512; off <<= 1) {
        int t = (threadIdx.x >= off) ? sm[threadIdx.x - off] : 0;
        __syncthreads();
        sm[threadIdx.x] += t;
        __syncthreads();
    }
    if (threadIdx.x < nchunks) cte[threadIdx.x] = sm[threadIdx.x] - v;
}

__global__ void k_scan3(const int* __restrict__ chunk_excl, const int* __restrict__ cte,
                        int* __restrict__ rowptr, int N, int total)
{
    int i = blockIdx.x * blockDim.x + threadIdx.x;
    if (i < N) rowptr[i] = chunk_excl[i] + cte[i >> 8];
    if (i == N) rowptr[N] = total;
}

__global__ void k_fill(const int* __restrict__ ei, const int* __restrict__ rowptr,
                       int* __restrict__ cursor, int* __restrict__ csr_src, int E, int N)
{
    int e = blockIdx.x * blockDim.x + threadIdx.x;
    if (e >= E + N) return;
    int s, d;
    if (e < E) { s = ei[e]; d = ei[E + e]; } else { s = d = e - E; }
    int pos = rowptr[d] + atomicAdd(&cursor[d], 1);
    csr_src[pos] = s;
}

// ---------------- K2: gather + softmax + aggregate + bias + LN + ReLU ----------------
// one wave per destination node; lane l owns channels 2l, 2l+1.
__global__ void k_gather(const int* __restrict__ csr_src, const int* __restrict__ rowptr,
                         const __hip_bfloat16* __restrict__ hB,
                         const float* __restrict__ asrc, const float* __restrict__ adst,
                         const float* __restrict__ bias, const float* __restrict__ gamma,
                         const float* __restrict__ beta, float* __restrict__ out, int N)
{
    int wave = threadIdx.x >> 6;
    int l = threadIdx.x & 63;
    int d = blockIdx.x * 4 + wave;
    if (d >= N) return;
    int head = l >> 4;                       // channels 2l,2l+1 -> head = (2l)>>5
    float ad = adst[d * NHEAD + head];
    int beg = rowptr[d], end = rowptr[d + 1];

    float accx = 0.f, accy = 0.f, den = 0.f;
    int s_next = (beg < end) ? csr_src[beg] : 0;
    for (int j = beg; j < end; ++j) {
        int s = s_next;
        if (j + 1 < end) s_next = csr_src[j + 1];
        float v = asrc[s * NHEAD + head] + ad;
        v = v > 0.f ? v : NEG_SLOPE * v;
        float ee = __expf(v);
        __hip_bfloat162 hb = ((const __hip_bfloat162*)hB)[(size_t)s * (OUT_DIM / 2) + l];
        float2 hf = __bfloat1622float2(hb);
        accx = fmaf(ee, hf.x, accx);
        accy = fmaf(ee, hf.y, accy);
        den += ee;
    }
    float inv = 1.f / (den + SM_EPS);
    float vx = accx * inv + bias[2 * l];
    float vy = accy * inv + bias[2 * l + 1];

    // LayerNorm over the 128 channels held by this wave
    float s1 = vx + vy;
    float s2 = vx * vx + vy * vy;
    #pragma unroll
    for (int m = 32; m >= 1; m >>= 1) {
        s1 += __shfl_xor(s1, m, 64);
        s2 += __shfl_xor(s2, m, 64);
    }
    float mean = s1 * (1.f / OUT_DIM);
    float var = s2 * (1.f / OUT_DIM) - mean * mean;
    float r = rsqrtf(var + LN_EPS);
    float ox = (vx - mean) * r * gamma[2 * l] + beta[2 * l];
    float oy = (vy - mean) * r * gamma[2 * l + 1] + beta[2 * l + 1];
    ox = ox > 0.f ? ox : 0.f;
    oy = oy > 0.f ? oy : 0.f;
    *reinterpret_cast<float2*>(&out[(size_t)d * OUT_DIM + 2 * l]) = make_float2(ox, oy);
}

extern "C" void kernel_launch(void* const* d_in, const int* in_sizes, int n_in,
                              void* d_out, int out_size, void* d_ws, size_t ws_size,
                              hipStream_t stream) {
    const float* x      = (const float*)d_in[0];
    const int*   ei     = (const int*)d_in[1];
    const float* W      = (const float*)d_in[2];
    const float* a_src  = (const float*)d_in[3];
    const float* a_dst  = (const float*)d_in[4];
    const float* bias   = (const float*)d_in[5];
    const float* gamma  = (const float*)d_in[6];
    const float* beta   = (const float*)d_in[7];
    float* out = (float*)d_out;

    const int N = in_sizes[0] / IN_DIM;
    const int E = in_sizes[1] / 2;
    const int TOT = E + N;
    const int nchunks = (N + SCAN_B - 1) / SCAN_B;   // 391 for N=100000 (<=512)

    // workspace layout
    char* p = (char*)d_ws;
    __hip_bfloat16* hB = (__hip_bfloat16*)p;  p += (size_t)N * OUT_DIM * sizeof(__hip_bfloat16);
    float* asrc   = (float*)p;                p += (size_t)N * NHEAD * sizeof(float);
    float* adst   = (float*)p;                p += (size_t)N * NHEAD * sizeof(float);
    int* deg      = (int*)p;                  p += (size_t)N * sizeof(int);   // reused as cursor
    int* chunk_excl = (int*)p;                p += (size_t)N * sizeof(int);
    int* rowptr   = (int*)p;                  p += (size_t)(N + 1) * sizeof(int);
    int* ct       = (int*)p;                  p += 1024 * sizeof(int);
    int* cte      = (int*)p;                  p += 1024 * sizeof(int);
    int* csr_src  = (int*)p;                  p += (size_t)TOT * sizeof(int);

    // K1: GEMM + alphas (independent of CSR build — runs first)
    k_gemm_alpha<<<(N + 3) / 4, 128, 0, stream>>>(x, W, a_src, a_dst, hB, asrc, adst, N);

    // CSR build
    hipMemsetAsync(deg, 0, (size_t)N * sizeof(int), stream);
    k_count<<<(TOT + 255) / 256, 256, 0, stream>>>(ei, deg, E, N);
    k_scan1<<<nchunks, SCAN_B, 0, stream>>>(deg, chunk_excl, ct, N);
    k_scan2<<<1, 512, 0, stream>>>(ct, cte, nchunks);
    k_scan3<<<(N + 256) / 256, 256, 0, stream>>>(chunk_excl, cte, rowptr, N, TOT);
    hipMemsetAsync(deg, 0, (size_t)N * sizeof(int), stream);   // cursor = 0
    k_fill<<<(TOT + 255) / 256, 256, 0, stream>>>(ei, rowptr, deg, csr_src, E, N);

    // gather + epilogue
    k_gather<<<(N + 3) / 4, 256, 0, stream>>>(csr_src, rowptr, hB, asrc, adst,
                                              bias, gamma, beta, out, N);
}

// Round 3
// 306.758 us; speedup vs baseline: 3.3216x; 1.2597x over previous
//
#include <hip/hip_runtime.h>
#include <hip/hip_bf16.h>
#include <math.h>

#define IN_DIM 128
#define OUT_DIM 128
#define NHEAD 4
#define HC 32
#define NEG_SLOPE 0.2f
#define LN_EPS 1e-5f
#define SM_EPS 1e-16f
#define SCAN_B 256

typedef __attribute__((ext_vector_type(8))) short bf16x8;
typedef __attribute__((ext_vector_type(4))) short short4v;
typedef __attribute__((ext_vector_type(4))) float f32x4;

__device__ __forceinline__ float leaky(float v) { return v > 0.f ? v : NEG_SLOPE * v; }

__device__ __forceinline__ short f2b(float f) {
    __hip_bfloat16 b = __float2bfloat16(f);
    return *reinterpret_cast<short*>(&b);
}

// byte offset into a tile of 256-byte rows, XOR row-swizzled (G4 fix)
__device__ __forceinline__ int swz(int row, int byteInRow) {
    return row * 256 + (byteInRow ^ ((row & 7) << 4));
}

// ---------------- P0: W[k][j] fp32 -> WtB[j][k] bf16 (global, 32 KB) ----------------
__global__ void k_prepW(const float* __restrict__ W, __hip_bfloat16* __restrict__ WtB)
{
    int t = blockIdx.x * 256 + threadIdx.x;
    if (t >= IN_DIM * OUT_DIM) return;
    int k = t >> 7, j = t & 127;
    WtB[j * IN_DIM + k] = __float2bfloat16(W[t]);
}

// ---------------- K1: h = x @ W via MFMA + alpha_src/alpha_dst ----------------
// block 256 threads (4 waves), 64 nodes per block. LDS: xs 16KB + Wt 32KB.
__global__ void k_gemm_mfma(const float* __restrict__ x, const __hip_bfloat16* __restrict__ WtB,
                            const float* __restrict__ a_src, const float* __restrict__ a_dst,
                            __hip_bfloat16* __restrict__ hB, float* __restrict__ asrc_out,
                            float* __restrict__ adst_out, int N)
{
    __shared__ __align__(16) char lds[49152];   // [0,16384): xs ; [16384,49152): Wt
    const int t = threadIdx.x;
    const int node0 = blockIdx.x * 64;

    // stage Wt: bf16 [col][k], swizzled rows (stride 256B)
    #pragma unroll
    for (int i = 0; i < 16; ++i) {              // 16384 elems / (256 thr * 4)
        int idx = (i * 256 + t) * 4;
        int col = idx >> 7, k = idx & 127;
        short4v w4 = *reinterpret_cast<const short4v*>((const short*)WtB + idx);
        *reinterpret_cast<short4v*>(lds + 16384 + swz(col, 2 * k)) = w4;
    }
    // stage xs: bf16 [row][k], swizzled
    #pragma unroll
    for (int i = 0; i < 8; ++i) {               // 8192 elems / (256 thr * 4)
        int idx = (i * 256 + t) * 4;
        int row = idx >> 7, k = idx & 127;
        int node = node0 + row;
        float4 xv = make_float4(0.f, 0.f, 0.f, 0.f);
        if (node < N) xv = *reinterpret_cast<const float4*>(x + (size_t)node * IN_DIM + k);
        short4v xb = { f2b(xv.x), f2b(xv.y), f2b(xv.z), f2b(xv.w) };
        *reinterpret_cast<short4v*>(lds + swz(row, 2 * k)) = xb;
    }
    __syncthreads();

    const int wave = t >> 6, l = t & 63;
    const int lr = l & 15, lg = l >> 4;

    // A-fragments: rows wave*16 + lr, k = kk*32 + lg*8 + j
    bf16x8 afrag[4];
    #pragma unroll
    for (int kk = 0; kk < 4; ++kk)
        afrag[kk] = *reinterpret_cast<bf16x8*>(lds + swz(wave * 16 + lr, kk * 64 + lg * 16));

    f32x4 acc[8];
    #pragma unroll
    for (int cg = 0; cg < 8; ++cg) acc[cg] = (f32x4){0.f, 0.f, 0.f, 0.f};

    #pragma unroll
    for (int cg = 0; cg < 8; ++cg) {
        #pragma unroll
        for (int kk = 0; kk < 4; ++kk) {
            bf16x8 b = *reinterpret_cast<bf16x8*>(lds + 16384 + swz(cg * 16 + lr, kk * 64 + lg * 16));
            acc[cg] = __builtin_amdgcn_mfma_f32_16x16x32_bf16(afrag[kk], b, acc[cg], 0, 0, 0);
        }
    }

    // store h (bf16): D[row][col]: row = wave*16 + lg*4 + q, col = cg*16 + lr
    #pragma unroll
    for (int q = 0; q < 4; ++q) {
        int node = node0 + wave * 16 + lg * 4 + q;
        if (node < N) {
            #pragma unroll
            for (int cg = 0; cg < 8; ++cg)
                hB[(size_t)node * OUT_DIM + cg * 16 + lr] = __float2bfloat16(acc[cg][q]);
        }
    }

    // alpha epilogue: per row, per head reduce over 32 channels
    #pragma unroll
    for (int q = 0; q < 4; ++q) {
        int node = node0 + wave * 16 + lg * 4 + q;
        #pragma unroll
        for (int hh = 0; hh < 4; ++hh) {
            float as0 = a_src[hh * HC + lr], as1 = a_src[hh * HC + 16 + lr];
            float ad0 = a_dst[hh * HC + lr], ad1 = a_dst[hh * HC + 16 + lr];
            float s = acc[2 * hh][q] * as0 + acc[2 * hh + 1][q] * as1;
            float d = acc[2 * hh][q] * ad0 + acc[2 * hh + 1][q] * ad1;
            #pragma unroll
            for (int m = 1; m < 16; m <<= 1) {
                s += __shfl_xor(s, m, 64);
                d += __shfl_xor(d, m, 64);
            }
            if (lr == 0 && node < N) {
                asrc_out[node * NHEAD + hh] = s;
                adst_out[node * NHEAD + hh] = d;
            }
        }
    }
}

// ---------------- CSR build ----------------
__global__ void k_count(const int* __restrict__ ei, int* __restrict__ deg, int E, int N)
{
    int e = blockIdx.x * blockDim.x + threadIdx.x;
    if (e >= E + N) return;
    int d = (e < E) ? ei[E + e] : (e - E);
    atomicAdd(&deg[d], 1);
}

__global__ void k_scan1(const int* __restrict__ deg, int* __restrict__ chunk_excl,
                        int* __restrict__ ct, int N)
{
    __shared__ int sm[SCAN_B];
    int i = blockIdx.x * SCAN_B + threadIdx.x;
    int v = (i < N) ? deg[i] : 0;
    sm[threadIdx.x] = v;
    __syncthreads();
    for (int off = 1; off < SCAN_B; off <<= 1) {
        int t = (threadIdx.x >= off) ? sm[threadIdx.x - off] : 0;
        __syncthreads();
        sm[threadIdx.x] += t;
        __syncthreads();
    }
    if (i < N) chunk_excl[i] = sm[threadIdx.x] - v;
    if (threadIdx.x == SCAN_B - 1) ct[blockIdx.x] = sm[threadIdx.x];
}

__global__ void k_scan2(const int* __restrict__ ct, int* __restrict__ cte, int nchunks)
{
    __shared__ int sm[512];
    int v = (threadIdx.x < nchunks) ? ct[threadIdx.x] : 0;
    sm[threadIdx.x] = v;
    __syncthreads();
    for (int off = 1; off < 512; off <<= 1) {
        int t = (threadIdx.x >= off) ? sm[threadIdx.x - off] : 0;
        __syncthreads();
        sm[threadIdx.x] += t;
        __syncthreads();
    }
    if (threadIdx.x < nchunks) cte[threadIdx.x] = sm[threadIdx.x] - v;
}

__global__ void k_scan3(const int* __restrict__ chunk_excl, const int* __restrict__ cte,
                        int* __restrict__ rowptr, int N, int total)
{
    int i = blockIdx.x * blockDim.x + threadIdx.x;
    if (i < N) rowptr[i] = chunk_excl[i] + cte[i >> 8];
    if (i == N) rowptr[N] = total;
}

__global__ void k_fill(const int* __restrict__ ei, const int* __restrict__ rowptr,
                       int* __restrict__ cursor, int* __restrict__ csr_src, int E, int N)
{
    int e = blockIdx.x * blockDim.x + threadIdx.x;
    if (e >= E + N) return;
    int s, d;
    if (e < E) { s = ei[e]; d = ei[E + e]; } else { s = d = e - E; }
    int pos = rowptr[d] + atomicAdd(&cursor[d], 1);
    csr_src[pos] = s;
}

// ---------------- K2: gather + softmax + aggregate + bias + LN + ReLU ----------------
// one wave per destination node; lane l owns channels 2l, 2l+1. 4-deep unroll for MLP.
__global__ void k_gather(const int* __restrict__ csr_src, const int* __restrict__ rowptr,
                         const __hip_bfloat16* __restrict__ hB,
                         const float* __restrict__ asrc, const float* __restrict__ adst,
                         const float* __restrict__ bias, const float* __restrict__ gamma,
                         const float* __restrict__ beta, float* __restrict__ out, int N)
{
    int wave = threadIdx.x >> 6;
    int l = threadIdx.x & 63;
    int d = blockIdx.x * 4 + wave;
    if (d >= N) return;
    int head = l >> 4;
    float ad = adst[d * NHEAD + head];
    int beg = rowptr[d], end = rowptr[d + 1];

    float ax0 = 0.f, ay0 = 0.f, dn0 = 0.f;
    float ax1 = 0.f, ay1 = 0.f, dn1 = 0.f;
    float ax2 = 0.f, ay2 = 0.f, dn2 = 0.f;
    float ax3 = 0.f, ay3 = 0.f, dn3 = 0.f;

    int j = beg;
    for (; j + 4 <= end; j += 4) {
        int s0 = csr_src[j], s1 = csr_src[j + 1], s2 = csr_src[j + 2], s3 = csr_src[j + 3];
        float v0 = asrc[s0 * NHEAD + head];
        float v1 = asrc[s1 * NHEAD + head];
        float v2 = asrc[s2 * NHEAD + head];
        float v3 = asrc[s3 * NHEAD + head];
        unsigned h0 = *reinterpret_cast<const unsigned*>(hB + (size_t)s0 * OUT_DIM + 2 * l);
        unsigned h1 = *reinterpret_cast<const unsigned*>(hB + (size_t)s1 * OUT_DIM + 2 * l);
        unsigned h2 = *reinterpret_cast<const unsigned*>(hB + (size_t)s2 * OUT_DIM + 2 * l);
        unsigned h3 = *reinterpret_cast<const unsigned*>(hB + (size_t)s3 * OUT_DIM + 2 * l);
        float e0 = __expf(leaky(v0 + ad));
        float e1 = __expf(leaky(v1 + ad));
        float e2 = __expf(leaky(v2 + ad));
        float e3 = __expf(leaky(v3 + ad));
        ax0 = fmaf(e0, __uint_as_float(h0 << 16), ax0);
        ay0 = fmaf(e0, __uint_as_float(h0 & 0xffff0000u), ay0);
        dn0 += e0;
        ax1 = fmaf(e1, __uint_as_float(h1 << 16), ax1);
        ay1 = fmaf(e1, __uint_as_float(h1 & 0xffff0000u), ay1);
        dn1 += e1;
        ax2 = fmaf(e2, __uint_as_float(h2 << 16), ax2);
        ay2 = fmaf(e2, __uint_as_float(h2 & 0xffff0000u), ay2);
        dn2 += e2;
        ax3 = fmaf(e3, __uint_as_float(h3 << 16), ax3);
        ay3 = fmaf(e3, __uint_as_float(h3 & 0xffff0000u), ay3);
        dn3 += e3;
    }
    for (; j < end; ++j) {
        int s0 = csr_src[j];
        float v0 = asrc[s0 * NHEAD + head];
        unsigned h0 = *reinterpret_cast<const unsigned*>(hB + (size_t)s0 * OUT_DIM + 2 * l);
        float e0 = __expf(leaky(v0 + ad));
        ax0 = fmaf(e0, __uint_as_float(h0 << 16), ax0);
        ay0 = fmaf(e0, __uint_as_float(h0 & 0xffff0000u), ay0);
        dn0 += e0;
    }
    float accx = (ax0 + ax1) + (ax2 + ax3);
    float accy = (ay0 + ay1) + (ay2 + ay3);
    float den  = (dn0 + dn1) + (dn2 + dn3);

    float inv = 1.f / (den + SM_EPS);
    float vx = accx * inv + bias[2 * l];
    float vy = accy * inv + bias[2 * l + 1];

    float s1 = vx + vy;
    float s2 = vx * vx + vy * vy;
    #pragma unroll
    for (int m = 32; m >= 1; m >>= 1) {
        s1 += __shfl_xor(s1, m, 64);
        s2 += __shfl_xor(s2, m, 64);
    }
    float mean = s1 * (1.f / OUT_DIM);
    float var = s2 * (1.f / OUT_DIM) - mean * mean;
    float r = rsqrtf(var + LN_EPS);
    float ox = (vx - mean) * r * gamma[2 * l] + beta[2 * l];
    float oy = (vy - mean) * r * gamma[2 * l + 1] + beta[2 * l + 1];
    ox = ox > 0.f ? ox : 0.f;
    oy = oy > 0.f ? oy : 0.f;
    *reinterpret_cast<float2*>(&out[(size_t)d * OUT_DIM + 2 * l]) = make_float2(ox, oy);
}

extern "C" void kernel_launch(void* const* d_in, const int* in_sizes, int n_in,
                              void* d_out, int out_size, void* d_ws, size_t ws_size,
                              hipStream_t stream) {
    const float* x      = (const float*)d_in[0];
    const int*   ei     = (const int*)d_in[1];
    const float* W      = (const float*)d_in[2];
    const float* a_src  = (const float*)d_in[3];
    const float* a_dst  = (const float*)d_in[4];
    const float* bias   = (const float*)d_in[5];
    const float* gamma  = (const float*)d_in[6];
    const float* beta   = (const float*)d_in[7];
    float* out = (float*)d_out;

    const int N = in_sizes[0] / IN_DIM;
    const int E = in_sizes[1] / 2;
    const int TOT = E + N;
    const int nchunks = (N + SCAN_B - 1) / SCAN_B;

    // workspace layout
    char* p = (char*)d_ws;
    __hip_bfloat16* hB = (__hip_bfloat16*)p;  p += (size_t)N * OUT_DIM * sizeof(__hip_bfloat16);
    __hip_bfloat16* WtB = (__hip_bfloat16*)p; p += (size_t)IN_DIM * OUT_DIM * sizeof(__hip_bfloat16);
    float* asrc   = (float*)p;                p += (size_t)N * NHEAD * sizeof(float);
    float* adst   = (float*)p;                p += (size_t)N * NHEAD * sizeof(float);
    int* deg      = (int*)p;                  p += (size_t)N * sizeof(int);   // reused as cursor
    int* chunk_excl = (int*)p;                p += (size_t)N * sizeof(int);
    int* rowptr   = (int*)p;                  p += (size_t)(N + 1) * sizeof(int);
    int* ct       = (int*)p;                  p += 1024 * sizeof(int);
    int* cte      = (int*)p;                  p += 1024 * sizeof(int);
    int* csr_src  = (int*)p;                  p += (size_t)TOT * sizeof(int);

    // W transpose + bf16 (32 KB)
    k_prepW<<<(IN_DIM * OUT_DIM + 255) / 256, 256, 0, stream>>>(W, WtB);

    // MFMA GEMM + alphas
    k_gemm_mfma<<<(N + 63) / 64, 256, 0, stream>>>(x, WtB, a_src, a_dst, hB, asrc, adst, N);

    // CSR build
    hipMemsetAsync(deg, 0, (size_t)N * sizeof(int), stream);
    k_count<<<(TOT + 255) / 256, 256, 0, stream>>>(ei, deg, E, N);
    k_scan1<<<nchunks, SCAN_B, 0, stream>>>(deg, chunk_excl, ct, N);
    k_scan2<<<1, 512, 0, stream>>>(ct, cte, nchunks);
    k_scan3<<<(N + 256) / 256, 256, 0, stream>>>(chunk_excl, cte, rowptr, N, TOT);
    hipMemsetAsync(deg, 0, (size_t)N * sizeof(int), stream);   // cursor = 0
    k_fill<<<(TOT + 255) / 256, 256, 0, stream>>>(ei, rowptr, deg, csr_src, E, N);

    // gather + epilogue
    k_gather<<<(N + 3) / 4, 256, 0, stream>>>(csr_src, rowptr, hB, asrc, adst,
                                              bias, gamma, beta, out, N);
}

// Round 4
// 194.327 us; speedup vs baseline: 5.2433x; 1.5786x over previous
//
#include <hip/hip_runtime.h>
#include <hip/hip_bf16.h>
#include <math.h>

#define IN_DIM 128
#define OUT_DIM 128
#define NHEAD 4
#define HC 32
#define NEG_SLOPE 0.2f
#define LN_EPS 1e-5f
#define SM_EPS 1e-16f

#define NB_SHIFT 9
#define BDST 512            // 1 << NB_SHIFT
#define NBUCK_MAX 256       // bucket arrays sized to 256 (actual ~196)
#define BIN_ITER 28
#define BIN_CHUNK (BIN_ITER * 256)

typedef __attribute__((ext_vector_type(8))) short bf16x8;
typedef __attribute__((ext_vector_type(4))) short short4v;
typedef __attribute__((ext_vector_type(4))) float f32x4;

__device__ __forceinline__ float leaky(float v) { return v > 0.f ? v : NEG_SLOPE * v; }

__device__ __forceinline__ short f2b(float f) {
    __hip_bfloat16 b = __float2bfloat16(f);
    return *reinterpret_cast<short*>(&b);
}

// byte offset into a tile of 256-byte rows, XOR row-swizzled (G4 fix)
__device__ __forceinline__ int swz(int row, int byteInRow) {
    return row * 256 + (byteInRow ^ ((row & 7) << 4));
}

// ---------------- P0: W[k][j] fp32 -> WtB[j][k] bf16 ----------------
__global__ void k_prepW(const float* __restrict__ W, __hip_bfloat16* __restrict__ WtB)
{
    int t = blockIdx.x * 256 + threadIdx.x;
    if (t >= IN_DIM * OUT_DIM) return;
    int k = t >> 7, j = t & 127;
    WtB[j * IN_DIM + k] = __float2bfloat16(W[t]);
}

// ---------------- K1: h = x @ W via MFMA + alpha_src/alpha_dst ----------------
__global__ void k_gemm_mfma(const float* __restrict__ x, const __hip_bfloat16* __restrict__ WtB,
                            const float* __restrict__ a_src, const float* __restrict__ a_dst,
                            __hip_bfloat16* __restrict__ hB, float* __restrict__ asrc_out,
                            float* __restrict__ adst_out, int N)
{
    __shared__ __align__(16) char lds[49152];   // [0,16384): xs ; [16384,49152): Wt
    const int t = threadIdx.x;
    const int node0 = blockIdx.x * 64;

    #pragma unroll
    for (int i = 0; i < 16; ++i) {
        int idx = (i * 256 + t) * 4;
        int col = idx >> 7, k = idx & 127;
        short4v w4 = *reinterpret_cast<const short4v*>((const short*)WtB + idx);
        *reinterpret_cast<short4v*>(lds + 16384 + swz(col, 2 * k)) = w4;
    }
    #pragma unroll
    for (int i = 0; i < 8; ++i) {
        int idx = (i * 256 + t) * 4;
        int row = idx >> 7, k = idx & 127;
        int node = node0 + row;
        float4 xv = make_float4(0.f, 0.f, 0.f, 0.f);
        if (node < N) xv = *reinterpret_cast<const float4*>(x + (size_t)node * IN_DIM + k);
        short4v xb = { f2b(xv.x), f2b(xv.y), f2b(xv.z), f2b(xv.w) };
        *reinterpret_cast<short4v*>(lds + swz(row, 2 * k)) = xb;
    }
    __syncthreads();

    const int wave = t >> 6, l = t & 63;
    const int lr = l & 15, lg = l >> 4;

    bf16x8 afrag[4];
    #pragma unroll
    for (int kk = 0; kk < 4; ++kk)
        afrag[kk] = *reinterpret_cast<bf16x8*>(lds + swz(wave * 16 + lr, kk * 64 + lg * 16));

    f32x4 acc[8];
    #pragma unroll
    for (int cg = 0; cg < 8; ++cg) acc[cg] = (f32x4){0.f, 0.f, 0.f, 0.f};

    #pragma unroll
    for (int cg = 0; cg < 8; ++cg) {
        #pragma unroll
        for (int kk = 0; kk < 4; ++kk) {
            bf16x8 b = *reinterpret_cast<bf16x8*>(lds + 16384 + swz(cg * 16 + lr, kk * 64 + lg * 16));
            acc[cg] = __builtin_amdgcn_mfma_f32_16x16x32_bf16(afrag[kk], b, acc[cg], 0, 0, 0);
        }
    }

    #pragma unroll
    for (int q = 0; q < 4; ++q) {
        int node = node0 + wave * 16 + lg * 4 + q;
        if (node < N) {
            #pragma unroll
            for (int cg = 0; cg < 8; ++cg)
                hB[(size_t)node * OUT_DIM + cg * 16 + lr] = __float2bfloat16(acc[cg][q]);
        }
    }

    #pragma unroll
    for (int q = 0; q < 4; ++q) {
        int node = node0 + wave * 16 + lg * 4 + q;
        #pragma unroll
        for (int hh = 0; hh < 4; ++hh) {
            float as0 = a_src[hh * HC + lr], as1 = a_src[hh * HC + 16 + lr];
            float ad0 = a_dst[hh * HC + lr], ad1 = a_dst[hh * HC + 16 + lr];
            float s = acc[2 * hh][q] * as0 + acc[2 * hh + 1][q] * as1;
            float d = acc[2 * hh][q] * ad0 + acc[2 * hh + 1][q] * ad1;
            #pragma unroll
            for (int m = 1; m < 16; m <<= 1) {
                s += __shfl_xor(s, m, 64);
                d += __shfl_xor(d, m, 64);
            }
            if (lr == 0 && node < N) {
                asrc_out[node * NHEAD + hh] = s;
                adst_out[node * NHEAD + hh] = d;
            }
        }
    }
}

// ---------------- binned CSR build ----------------
__global__ void k_hist(const int* __restrict__ ei, int* __restrict__ bcnt, int E, int N)
{
    __shared__ int h[NBUCK_MAX];
    for (int i = threadIdx.x; i < NBUCK_MAX; i += blockDim.x) h[i] = 0;
    __syncthreads();
    int tot = E + N;
    for (int e = blockIdx.x * blockDim.x + threadIdx.x; e < tot; e += gridDim.x * blockDim.x) {
        int d = (e < E) ? ei[E + e] : (e - E);
        atomicAdd(&h[d >> NB_SHIFT], 1);
    }
    __syncthreads();
    for (int i = threadIdx.x; i < NBUCK_MAX; i += blockDim.x)
        if (h[i]) atomicAdd(&bcnt[i], h[i]);
}

__global__ void k_scanB(const int* __restrict__ bcnt, int* __restrict__ bbase,
                        int* __restrict__ bcur, int tot)
{
    __shared__ int sm[NBUCK_MAX];
    int t = threadIdx.x;                      // 256 threads
    int v = bcnt[t];
    sm[t] = v;
    __syncthreads();
    for (int off = 1; off < NBUCK_MAX; off <<= 1) {
        int tmp = (t >= off) ? sm[t - off] : 0;
        __syncthreads();
        sm[t] += tmp;
        __syncthreads();
    }
    int excl = sm[t] - v;
    bbase[t] = excl;
    bcur[t] = excl;
    if (t == NBUCK_MAX - 1) bbase[NBUCK_MAX] = tot;
}

__global__ void k_bin(const int* __restrict__ ei, int* __restrict__ bcur,
                      int2* __restrict__ binned, int E, int N)
{
    __shared__ int cnt[NBUCK_MAX];
    __shared__ int gb[NBUCK_MAX];
    int t = threadIdx.x;
    int tot = E + N;
    int base = blockIdx.x * BIN_CHUNK;
    for (int i = t; i < NBUCK_MAX; i += 256) cnt[i] = 0;
    __syncthreads();

    int rk[BIN_ITER], bk[BIN_ITER];
    #pragma unroll
    for (int k = 0; k < BIN_ITER; ++k) {
        int e = base + k * 256 + t;
        bk[k] = -1; rk[k] = 0;
        if (e < tot) {
            int d = (e < E) ? ei[E + e] : (e - E);
            int b = d >> NB_SHIFT;
            bk[k] = b;
            rk[k] = atomicAdd(&cnt[b], 1);
        }
    }
    __syncthreads();
    for (int i = t; i < NBUCK_MAX; i += 256)
        gb[i] = cnt[i] ? atomicAdd(&bcur[i], cnt[i]) : 0;
    __syncthreads();
    #pragma unroll
    for (int k = 0; k < BIN_ITER; ++k) {
        int e = base + k * 256 + t;
        if (e < tot) {
            int s, d;
            if (e < E) { s = ei[e]; d = ei[E + e]; } else { s = d = e - E; }
            binned[gb[bk[k]] + rk[k]] = make_int2(s, d);
        }
    }
}

__global__ void k_bucket_csr(const int2* __restrict__ binned, const int* __restrict__ bbase,
                             int* __restrict__ rowptr, int* __restrict__ csr_src,
                             int N, int tot, int nbuck)
{
    __shared__ int cnt[BDST];
    __shared__ int s2[256];
    int b = blockIdx.x;
    int t = threadIdx.x;
    int d0 = b << NB_SHIFT;
    int ebase = bbase[b], eend = bbase[b + 1];
    int ne = eend - ebase;
    cnt[t] = 0; cnt[t + 256] = 0;
    __syncthreads();
    for (int i = t; i < ne; i += 256) {
        int2 p = binned[ebase + i];
        atomicAdd(&cnt[p.y - d0], 1);
    }
    __syncthreads();
    int c0 = cnt[2 * t], c1 = cnt[2 * t + 1];
    s2[t] = c0 + c1;
    __syncthreads();
    for (int off = 1; off < 256; off <<= 1) {
        int tmp = (t >= off) ? s2[t - off] : 0;
        __syncthreads();
        s2[t] += tmp;
        __syncthreads();
    }
    int e0 = (t ? s2[t - 1] : 0);
    cnt[2 * t] = e0;
    cnt[2 * t + 1] = e0 + c0;
    if (d0 + 2 * t < N)     rowptr[d0 + 2 * t]     = ebase + e0;
    if (d0 + 2 * t + 1 < N) rowptr[d0 + 2 * t + 1] = ebase + e0 + c0;
    if (b == nbuck - 1 && t == 0) rowptr[N] = tot;
    __syncthreads();
    for (int i = t; i < ne; i += 256) {
        int2 p = binned[ebase + i];
        int r = atomicAdd(&cnt[p.y - d0], 1);
        csr_src[ebase + r] = p.x;
    }
}

// ---------------- K2: gather + softmax + aggregate + bias + LN + ReLU ----------------
__global__ void k_gather(const int* __restrict__ csr_src, const int* __restrict__ rowptr,
                         const __hip_bfloat16* __restrict__ hB,
                         const float* __restrict__ asrc, const float* __restrict__ adst,
                         const float* __restrict__ bias, const float* __restrict__ gamma,
                         const float* __restrict__ beta, float* __restrict__ out, int N)
{
    int wave = threadIdx.x >> 6;
    int l = threadIdx.x & 63;
    int d = blockIdx.x * 4 + wave;
    if (d >= N) return;
    int head = l >> 4;
    unsigned hoff = (unsigned)(l << 2);          // byte offset of channel pair in h row
    unsigned aoff = (unsigned)(head << 2);       // byte offset of head in asrc row
    const char* hp = (const char*)hB;
    const char* ap = (const char*)asrc;
    float ad = adst[d * NHEAD + head];
    int beg = rowptr[d], end = rowptr[d + 1];

    float ax0 = 0.f, ay0 = 0.f, dn0 = 0.f;
    float ax1 = 0.f, ay1 = 0.f, dn1 = 0.f;
    float ax2 = 0.f, ay2 = 0.f, dn2 = 0.f;
    float ax3 = 0.f, ay3 = 0.f, dn3 = 0.f;

    int j = beg;
    for (; j + 4 <= end; j += 4) {
        unsigned s0 = (unsigned)csr_src[j],     s1 = (unsigned)csr_src[j + 1];
        unsigned s2 = (unsigned)csr_src[j + 2], s3 = (unsigned)csr_src[j + 3];
        float v0 = *(const float*)(ap + (s0 << 4) + aoff);
        float v1 = *(const float*)(ap + (s1 << 4) + aoff);
        float v2 = *(const float*)(ap + (s2 << 4) + aoff);
        float v3 = *(const float*)(ap + (s3 << 4) + aoff);
        unsigned h0 = *(const unsigned*)(hp + (s0 << 8) + hoff);
        unsigned h1 = *(const unsigned*)(hp + (s1 << 8) + hoff);
        unsigned h2 = *(const unsigned*)(hp + (s2 << 8) + hoff);
        unsigned h3 = *(const unsigned*)(hp + (s3 << 8) + hoff);
        float e0 = __expf(leaky(v0 + ad));
        float e1 = __expf(leaky(v1 + ad));
        float e2 = __expf(leaky(v2 + ad));
        float e3 = __expf(leaky(v3 + ad));
        ax0 = fmaf(e0, __uint_as_float(h0 << 16), ax0);
        ay0 = fmaf(e0, __uint_as_float(h0 & 0xffff0000u), ay0);
        dn0 += e0;
        ax1 = fmaf(e1, __uint_as_float(h1 << 16), ax1);
        ay1 = fmaf(e1, __uint_as_float(h1 & 0xffff0000u), ay1);
        dn1 += e1;
        ax2 = fmaf(e2, __uint_as_float(h2 << 16), ax2);
        ay2 = fmaf(e2, __uint_as_float(h2 & 0xffff0000u), ay2);
        dn2 += e2;
        ax3 = fmaf(e3, __uint_as_float(h3 << 16), ax3);
        ay3 = fmaf(e3, __uint_as_float(h3 & 0xffff0000u), ay3);
        dn3 += e3;
    }
    for (; j < end; ++j) {
        unsigned s0 = (unsigned)csr_src[j];
        float v0 = *(const float*)(ap + (s0 << 4) + aoff);
        unsigned h0 = *(const unsigned*)(hp + (s0 << 8) + hoff);
        float e0 = __expf(leaky(v0 + ad));
        ax0 = fmaf(e0, __uint_as_float(h0 << 16), ax0);
        ay0 = fmaf(e0, __uint_as_float(h0 & 0xffff0000u), ay0);
        dn0 += e0;
    }
    float accx = (ax0 + ax1) + (ax2 + ax3);
    float accy = (ay0 + ay1) + (ay2 + ay3);
    float den  = (dn0 + dn1) + (dn2 + dn3);

    float inv = 1.f / (den + SM_EPS);
    float vx = accx * inv + bias[2 * l];
    float vy = accy * inv + bias[2 * l + 1];

    float s1 = vx + vy;
    float s2 = vx * vx + vy * vy;
    #pragma unroll
    for (int m = 32; m >= 1; m >>= 1) {
        s1 += __shfl_xor(s1, m, 64);
        s2 += __shfl_xor(s2, m, 64);
    }
    float mean = s1 * (1.f / OUT_DIM);
    float var = s2 * (1.f / OUT_DIM) - mean * mean;
    float r = rsqrtf(var + LN_EPS);
    float ox = (vx - mean) * r * gamma[2 * l] + beta[2 * l];
    float oy = (vy - mean) * r * gamma[2 * l + 1] + beta[2 * l + 1];
    ox = ox > 0.f ? ox : 0.f;
    oy = oy > 0.f ? oy : 0.f;
    *reinterpret_cast<float2*>(&out[(size_t)d * OUT_DIM + 2 * l]) = make_float2(ox, oy);
}

extern "C" void kernel_launch(void* const* d_in, const int* in_sizes, int n_in,
                              void* d_out, int out_size, void* d_ws, size_t ws_size,
                              hipStream_t stream) {
    const float* x      = (const float*)d_in[0];
    const int*   ei     = (const int*)d_in[1];
    const float* W      = (const float*)d_in[2];
    const float* a_src  = (const float*)d_in[3];
    const float* a_dst  = (const float*)d_in[4];
    const float* bias   = (const float*)d_in[5];
    const float* gamma  = (const float*)d_in[6];
    const float* beta   = (const float*)d_in[7];
    float* out = (float*)d_out;

    const int N = in_sizes[0] / IN_DIM;
    const int E = in_sizes[1] / 2;
    const int TOT = E + N;
    const int nbuck = (N + BDST - 1) >> NB_SHIFT;

    // workspace layout
    char* p = (char*)d_ws;
    __hip_bfloat16* hB = (__hip_bfloat16*)p;  p += (size_t)N * OUT_DIM * sizeof(__hip_bfloat16);
    __hip_bfloat16* WtB = (__hip_bfloat16*)p; p += (size_t)IN_DIM * OUT_DIM * sizeof(__hip_bfloat16);
    float* asrc   = (float*)p;                p += (size_t)N * NHEAD * sizeof(float);
    float* adst   = (float*)p;                p += (size_t)N * NHEAD * sizeof(float);
    int* bcnt     = (int*)p;                  p += NBUCK_MAX * sizeof(int);
    int* bbase    = (int*)p;                  p += (NBUCK_MAX + 1) * sizeof(int);
    int* bcur     = (int*)p;                  p += NBUCK_MAX * sizeof(int);
    int* rowptr   = (int*)p;                  p += (size_t)(N + 1) * sizeof(int);
    int2* binned  = (int2*)p;                 p += (size_t)TOT * sizeof(int2);
    int* csr_src  = (int*)p;                  p += (size_t)TOT * sizeof(int);

    // W transpose + bf16
    k_prepW<<<(IN_DIM * OUT_DIM + 255) / 256, 256, 0, stream>>>(W, WtB);

    // MFMA GEMM + alphas
    k_gemm_mfma<<<(N + 63) / 64, 256, 0, stream>>>(x, WtB, a_src, a_dst, hB, asrc, adst, N);

    // binned CSR build
    hipMemsetAsync(bcnt, 0, NBUCK_MAX * sizeof(int), stream);
    k_hist<<<256, 256, 0, stream>>>(ei, bcnt, E, N);
    k_scanB<<<1, NBUCK_MAX, 0, stream>>>(bcnt, bbase, bcur, TOT);
    k_bin<<<(TOT + BIN_CHUNK - 1) / BIN_CHUNK, 256, 0, stream>>>(ei, bcur, binned, E, N);
    k_bucket_csr<<<nbuck, 256, 0, stream>>>(binned, bbase, rowptr, csr_src, N, TOT, nbuck);

    // gather + epilogue
    k_gather<<<(N + 3) / 4, 256, 0, stream>>>(csr_src, rowptr, hB, asrc, adst,
                                              bias, gamma, beta, out, N);
}

// Round 5
// 188.856 us; speedup vs baseline: 5.3952x; 1.0290x over previous
//
#include <hip/hip_runtime.h>
#include <hip/hip_bf16.h>
#include <math.h>

#define IN_DIM 128
#define OUT_DIM 128
#define NHEAD 4
#define HC 32
#define NEG_SLOPE 0.2f
#define LN_EPS 1e-5f
#define SM_EPS 1e-16f

#define NB_SHIFT 9
#define BDST 512            // 1 << NB_SHIFT
#define NBUCK_MAX 256
#define BIN_ITER 28
#define BIN_CHUNK (BIN_ITER * 256)
#define SRC_BITS 17         // N < 131072
#define SRC_MASK ((1u << SRC_BITS) - 1u)

typedef __attribute__((ext_vector_type(8))) short bf16x8;
typedef __attribute__((ext_vector_type(4))) short short4v;
typedef __attribute__((ext_vector_type(4))) float f32x4;

__device__ __forceinline__ float leaky(float v) { return v > 0.f ? v : NEG_SLOPE * v; }

__device__ __forceinline__ short f2b(float f) {
    __hip_bfloat16 b = __float2bfloat16(f);
    return *reinterpret_cast<short*>(&b);
}

// byte offset into a tile of 256-byte rows, XOR row-swizzled (G4 fix)
__device__ __forceinline__ int swz(int row, int byteInRow) {
    return row * 256 + (byteInRow ^ ((row & 7) << 4));
}

// ---------------- K0: prepW (blocks 0..63) + dst histogram (all blocks) ----------------
__global__ void k_prep(const float* __restrict__ W, __hip_bfloat16* __restrict__ WtB,
                       const int* __restrict__ ei, int* __restrict__ bcnt, int E, int N)
{
    // part 1: W[k][j] -> WtB[j][k] bf16 (16384 elements over first 64 blocks)
    int t0 = blockIdx.x * 256 + threadIdx.x;
    if (t0 < IN_DIM * OUT_DIM) {
        int k = t0 >> 7, j = t0 & 127;
        WtB[j * IN_DIM + k] = __float2bfloat16(W[t0]);
    }
    // part 2: histogram of dst buckets
    __shared__ int h[NBUCK_MAX];
    for (int i = threadIdx.x; i < NBUCK_MAX; i += blockDim.x) h[i] = 0;
    __syncthreads();
    int tot = E + N;
    for (int e = blockIdx.x * blockDim.x + threadIdx.x; e < tot; e += gridDim.x * blockDim.x) {
        int d = (e < E) ? ei[E + e] : (e - E);
        atomicAdd(&h[d >> NB_SHIFT], 1);
    }
    __syncthreads();
    for (int i = threadIdx.x; i < NBUCK_MAX; i += blockDim.x)
        if (h[i]) atomicAdd(&bcnt[i], h[i]);
}

// ---------------- K1: h = x @ W via MFMA + alpha_src/alpha_dst ----------------
__global__ void k_gemm_mfma(const float* __restrict__ x, const __hip_bfloat16* __restrict__ WtB,
                            const float* __restrict__ a_src, const float* __restrict__ a_dst,
                            __hip_bfloat16* __restrict__ hB, float* __restrict__ asrc_out,
                            float* __restrict__ adst_out, int N)
{
    __shared__ __align__(16) char lds[49152];   // [0,16384): xs ; [16384,49152): Wt
    const int t = threadIdx.x;
    const int node0 = blockIdx.x * 64;

    #pragma unroll
    for (int i = 0; i < 16; ++i) {
        int idx = (i * 256 + t) * 4;
        int col = idx >> 7, k = idx & 127;
        short4v w4 = *reinterpret_cast<const short4v*>((const short*)WtB + idx);
        *reinterpret_cast<short4v*>(lds + 16384 + swz(col, 2 * k)) = w4;
    }
    #pragma unroll
    for (int i = 0; i < 8; ++i) {
        int idx = (i * 256 + t) * 4;
        int row = idx >> 7, k = idx & 127;
        int node = node0 + row;
        float4 xv = make_float4(0.f, 0.f, 0.f, 0.f);
        if (node < N) xv = *reinterpret_cast<const float4*>(x + (size_t)node * IN_DIM + k);
        short4v xb = { f2b(xv.x), f2b(xv.y), f2b(xv.z), f2b(xv.w) };
        *reinterpret_cast<short4v*>(lds + swz(row, 2 * k)) = xb;
    }
    __syncthreads();

    const int wave = t >> 6, l = t & 63;
    const int lr = l & 15, lg = l >> 4;

    bf16x8 afrag[4];
    #pragma unroll
    for (int kk = 0; kk < 4; ++kk)
        afrag[kk] = *reinterpret_cast<bf16x8*>(lds + swz(wave * 16 + lr, kk * 64 + lg * 16));

    f32x4 acc[8];
    #pragma unroll
    for (int cg = 0; cg < 8; ++cg) acc[cg] = (f32x4){0.f, 0.f, 0.f, 0.f};

    #pragma unroll
    for (int cg = 0; cg < 8; ++cg) {
        #pragma unroll
        for (int kk = 0; kk < 4; ++kk) {
            bf16x8 b = *reinterpret_cast<bf16x8*>(lds + 16384 + swz(cg * 16 + lr, kk * 64 + lg * 16));
            acc[cg] = __builtin_amdgcn_mfma_f32_16x16x32_bf16(afrag[kk], b, acc[cg], 0, 0, 0);
        }
    }

    #pragma unroll
    for (int q = 0; q < 4; ++q) {
        int node = node0 + wave * 16 + lg * 4 + q;
        if (node < N) {
            #pragma unroll
            for (int cg = 0; cg < 8; ++cg)
                hB[(size_t)node * OUT_DIM + cg * 16 + lr] = __float2bfloat16(acc[cg][q]);
        }
    }

    #pragma unroll
    for (int q = 0; q < 4; ++q) {
        int node = node0 + wave * 16 + lg * 4 + q;
        #pragma unroll
        for (int hh = 0; hh < 4; ++hh) {
            float as0 = a_src[hh * HC + lr], as1 = a_src[hh * HC + 16 + lr];
            float ad0 = a_dst[hh * HC + lr], ad1 = a_dst[hh * HC + 16 + lr];
            float s = acc[2 * hh][q] * as0 + acc[2 * hh + 1][q] * as1;
            float d = acc[2 * hh][q] * ad0 + acc[2 * hh + 1][q] * ad1;
            #pragma unroll
            for (int m = 1; m < 16; m <<= 1) {
                s += __shfl_xor(s, m, 64);
                d += __shfl_xor(d, m, 64);
            }
            if (lr == 0 && node < N) {
                asrc_out[node * NHEAD + hh] = s;
                adst_out[node * NHEAD + hh] = d;
            }
        }
    }
}

// ---------------- K2: bin edges into dst buckets (packed uint32) ----------------
__global__ void k_bin(const int* __restrict__ ei, const int* __restrict__ bcnt,
                      int* __restrict__ bcur, unsigned* __restrict__ binned, int E, int N)
{
    __shared__ int cnt[NBUCK_MAX];
    __shared__ int gb[NBUCK_MAX];
    __shared__ int sc[NBUCK_MAX];
    int t = threadIdx.x;
    int tot = E + N;
    int base = blockIdx.x * BIN_CHUNK;

    // in-block exclusive scan of bcnt -> bucket base
    int bv = bcnt[t];
    sc[t] = bv;
    __syncthreads();
    #pragma unroll
    for (int off = 1; off < NBUCK_MAX; off <<= 1) {
        int tmp = (t >= off) ? sc[t - off] : 0;
        __syncthreads();
        sc[t] += tmp;
        __syncthreads();
    }
    int bbase_t = sc[t] - bv;
    cnt[t] = 0;
    __syncthreads();

    int rk[BIN_ITER], bk[BIN_ITER];
    #pragma unroll
    for (int k = 0; k < BIN_ITER; ++k) {
        int e = base + k * 256 + t;
        bk[k] = -1; rk[k] = 0;
        if (e < tot) {
            int d = (e < E) ? ei[E + e] : (e - E);
            int b = d >> NB_SHIFT;
            bk[k] = b;
            rk[k] = atomicAdd(&cnt[b], 1);
        }
    }
    __syncthreads();
    gb[t] = cnt[t] ? (bbase_t + atomicAdd(&bcur[t], cnt[t])) : 0;
    __syncthreads();
    #pragma unroll
    for (int k = 0; k < BIN_ITER; ++k) {
        int e = base + k * 256 + t;
        if (e < tot) {
            int s, d;
            if (e < E) { s = ei[e]; d = ei[E + e]; } else { s = d = e - E; }
            binned[gb[bk[k]] + rk[k]] = (unsigned)s | ((unsigned)(d & (BDST - 1)) << SRC_BITS);
        }
    }
}

// ---------------- K3: per-bucket local CSR ----------------
__global__ void k_bucket_csr(const unsigned* __restrict__ binned, const int* __restrict__ bcnt,
                             int* __restrict__ rowptr, int* __restrict__ csr_src,
                             int N, int tot, int nbuck)
{
    __shared__ int cnt[BDST];
    __shared__ int s2[256];
    int b = blockIdx.x;
    int t = threadIdx.x;
    int d0 = b << NB_SHIFT;

    // in-block scan of bcnt for this bucket's base
    int bv = bcnt[t];
    s2[t] = bv;
    __syncthreads();
    #pragma unroll
    for (int off = 1; off < NBUCK_MAX; off <<= 1) {
        int tmp = (t >= off) ? s2[t - off] : 0;
        __syncthreads();
        s2[t] += tmp;
        __syncthreads();
    }
    __shared__ int ebase_s, ne_s;
    if (t == b) { ebase_s = s2[t] - bv; ne_s = bv; }
    __syncthreads();
    int ebase = ebase_s, ne = ne_s;

    cnt[t] = 0; cnt[t + 256] = 0;
    __syncthreads();
    for (int i = t; i < ne; i += 256) {
        unsigned p = binned[ebase + i];
        atomicAdd(&cnt[p >> SRC_BITS], 1);
    }
    __syncthreads();
    int c0 = cnt[2 * t], c1 = cnt[2 * t + 1];
    s2[t] = c0 + c1;
    __syncthreads();
    #pragma unroll
    for (int off = 1; off < 256; off <<= 1) {
        int tmp = (t >= off) ? s2[t - off] : 0;
        __syncthreads();
        s2[t] += tmp;
        __syncthreads();
    }
    int e0 = (t ? s2[t - 1] : 0);
    cnt[2 * t] = e0;
    cnt[2 * t + 1] = e0 + c0;
    if (d0 + 2 * t < N)     rowptr[d0 + 2 * t]     = ebase + e0;
    if (d0 + 2 * t + 1 < N) rowptr[d0 + 2 * t + 1] = ebase + e0 + c0;
    if (b == nbuck - 1 && t == 0) rowptr[N] = tot;
    __syncthreads();
    for (int i = t; i < ne; i += 256) {
        unsigned p = binned[ebase + i];
        int r = atomicAdd(&cnt[p >> SRC_BITS], 1);
        csr_src[ebase + r] = (int)(p & SRC_MASK);
    }
}

// ---------------- K4: gather + softmax + aggregate + bias + LN + ReLU ----------------
// one wave per dst node; lane l owns channels 2l,2l+1 (head = l>>4).
// ee computed batched: lane l computes ee for (edge l&15, head l>>4) per 16-edge chunk.
__global__ void k_gather(const int* __restrict__ csr_src, const int* __restrict__ rowptr,
                         const __hip_bfloat16* __restrict__ hB,
                         const float* __restrict__ asrc, const float* __restrict__ adst,
                         const float* __restrict__ bias, const float* __restrict__ gamma,
                         const float* __restrict__ beta, float* __restrict__ out, int N)
{
    int wave = threadIdx.x >> 6;
    int l = threadIdx.x & 63;
    int d = blockIdx.x * 4 + wave;
    if (d >= N) return;
    int head = l >> 4;
    unsigned hoff = (unsigned)(l << 2);          // byte offset of channel pair in h row
    unsigned aoff = (unsigned)(head << 2);       // byte offset of head in asrc row
    int lsel = l & 48;                           // shfl base: lane group start for my head
    const char* hp = (const char*)hB;
    const char* ap = (const char*)asrc;
    float ad = adst[d * NHEAD + head];
    int beg = rowptr[d], end = rowptr[d + 1];

    float accx = 0.f, accy = 0.f, den = 0.f;

    int c = beg;
    for (; c + 16 <= end; c += 16) {
        // batch: my edge = c + (l&15), my head = l>>4
        unsigned smine = (unsigned)csr_src[c + (l & 15)];
        float v = *(const float*)(ap + (smine << 4) + aoff);
        float ee = __expf(leaky(v + ad));
        #pragma unroll
        for (int e = 0; e < 16; ++e) {
            float eeb = __shfl(ee, lsel + e, 64);
            unsigned sb = (unsigned)__shfl((int)smine, e, 64);   // lane e holds edge e's src
            unsigned hv = *(const unsigned*)(hp + (sb << 8) + hoff);
            accx = fmaf(eeb, __uint_as_float(hv << 16), accx);
            accy = fmaf(eeb, __uint_as_float(hv & 0xffff0000u), accy);
            den += eeb;
        }
    }

    // tail < 16 edges: 4-chain unrolled per-lane path
    float ax1 = 0.f, ay1 = 0.f, dn1 = 0.f;
    float ax2 = 0.f, ay2 = 0.f, dn2 = 0.f;
    float ax3 = 0.f, ay3 = 0.f, dn3 = 0.f;
    int j = c;
    for (; j + 4 <= end; j += 4) {
        unsigned s0 = (unsigned)csr_src[j],     s1 = (unsigned)csr_src[j + 1];
        unsigned s2 = (unsigned)csr_src[j + 2], s3 = (unsigned)csr_src[j + 3];
        float v0 = *(const float*)(ap + (s0 << 4) + aoff);
        float v1 = *(const float*)(ap + (s1 << 4) + aoff);
        float v2 = *(const float*)(ap + (s2 << 4) + aoff);
        float v3 = *(const float*)(ap + (s3 << 4) + aoff);
        unsigned h0 = *(const unsigned*)(hp + (s0 << 8) + hoff);
        unsigned h1 = *(const unsigned*)(hp + (s1 << 8) + hoff);
        unsigned h2 = *(const unsigned*)(hp + (s2 << 8) + hoff);
        unsigned h3 = *(const unsigned*)(hp + (s3 << 8) + hoff);
        float e0 = __expf(leaky(v0 + ad));
        float e1 = __expf(leaky(v1 + ad));
        float e2 = __expf(leaky(v2 + ad));
        float e3 = __expf(leaky(v3 + ad));
        accx = fmaf(e0, __uint_as_float(h0 << 16), accx);
        accy = fmaf(e0, __uint_as_float(h0 & 0xffff0000u), accy);
        den += e0;
        ax1 = fmaf(e1, __uint_as_float(h1 << 16), ax1);
        ay1 = fmaf(e1, __uint_as_float(h1 & 0xffff0000u), ay1);
        dn1 += e1;
        ax2 = fmaf(e2, __uint_as_float(h2 << 16), ax2);
        ay2 = fmaf(e2, __uint_as_float(h2 & 0xffff0000u), ay2);
        dn2 += e2;
        ax3 = fmaf(e3, __uint_as_float(h3 << 16), ax3);
        ay3 = fmaf(e3, __uint_as_float(h3 & 0xffff0000u), ay3);
        dn3 += e3;
    }
    for (; j < end; ++j) {
        unsigned s0 = (unsigned)csr_src[j];
        float v0 = *(const float*)(ap + (s0 << 4) + aoff);
        unsigned h0 = *(const unsigned*)(hp + (s0 << 8) + hoff);
        float e0 = __expf(leaky(v0 + ad));
        accx = fmaf(e0, __uint_as_float(h0 << 16), accx);
        accy = fmaf(e0, __uint_as_float(h0 & 0xffff0000u), accy);
        den += e0;
    }
    accx += (ax1 + ax2) + ax3;
    accy += (ay1 + ay2) + ay3;
    den  += (dn1 + dn2) + dn3;

    float inv = 1.f / (den + SM_EPS);
    float vx = accx * inv + bias[2 * l];
    float vy = accy * inv + bias[2 * l + 1];

    float s1 = vx + vy;
    float s2 = vx * vx + vy * vy;
    #pragma unroll
    for (int m = 32; m >= 1; m >>= 1) {
        s1 += __shfl_xor(s1, m, 64);
        s2 += __shfl_xor(s2, m, 64);
    }
    float mean = s1 * (1.f / OUT_DIM);
    float var = s2 * (1.f / OUT_DIM) - mean * mean;
    float r = rsqrtf(var + LN_EPS);
    float ox = (vx - mean) * r * gamma[2 * l] + beta[2 * l];
    float oy = (vy - mean) * r * gamma[2 * l + 1] + beta[2 * l + 1];
    ox = ox > 0.f ? ox : 0.f;
    oy = oy > 0.f ? oy : 0.f;
    *reinterpret_cast<float2*>(&out[(size_t)d * OUT_DIM + 2 * l]) = make_float2(ox, oy);
}

extern "C" void kernel_launch(void* const* d_in, const int* in_sizes, int n_in,
                              void* d_out, int out_size, void* d_ws, size_t ws_size,
                              hipStream_t stream) {
    const float* x      = (const float*)d_in[0];
    const int*   ei     = (const int*)d_in[1];
    const float* W      = (const float*)d_in[2];
    const float* a_src  = (const float*)d_in[3];
    const float* a_dst  = (const float*)d_in[4];
    const float* bias   = (const float*)d_in[5];
    const float* gamma  = (const float*)d_in[6];
    const float* beta   = (const float*)d_in[7];
    float* out = (float*)d_out;

    const int N = in_sizes[0] / IN_DIM;
    const int E = in_sizes[1] / 2;
    const int TOT = E + N;
    const int nbuck = (N + BDST - 1) >> NB_SHIFT;

    // workspace layout
    char* p = (char*)d_ws;
    __hip_bfloat16* hB = (__hip_bfloat16*)p;  p += (size_t)N * OUT_DIM * sizeof(__hip_bfloat16);
    __hip_bfloat16* WtB = (__hip_bfloat16*)p; p += (size_t)IN_DIM * OUT_DIM * sizeof(__hip_bfloat16);
    float* asrc   = (float*)p;                p += (size_t)N * NHEAD * sizeof(float);
    float* adst   = (float*)p;                p += (size_t)N * NHEAD * sizeof(float);
    int* bcnt     = (int*)p;                  p += NBUCK_MAX * sizeof(int);
    int* bcur     = (int*)p;                  p += NBUCK_MAX * sizeof(int);
    int* rowptr   = (int*)p;                  p += (size_t)(N + 1) * sizeof(int);
    unsigned* binned = (unsigned*)p;          p += (size_t)TOT * sizeof(unsigned);
    int* csr_src  = (int*)p;                  p += (size_t)TOT * sizeof(int);

    // zero bcnt + bcur in one memset (adjacent)
    hipMemsetAsync(bcnt, 0, 2 * NBUCK_MAX * sizeof(int), stream);

    // prepW + histogram
    k_prep<<<256, 256, 0, stream>>>(W, WtB, ei, bcnt, E, N);

    // MFMA GEMM + alphas
    k_gemm_mfma<<<(N + 63) / 64, 256, 0, stream>>>(x, WtB, a_src, a_dst, hB, asrc, adst, N);

    // bin (packed) + per-bucket CSR
    k_bin<<<(TOT + BIN_CHUNK - 1) / BIN_CHUNK, 256, 0, stream>>>(ei, bcnt, bcur, binned, E, N);
    k_bucket_csr<<<nbuck, 256, 0, stream>>>(binned, bcnt, rowptr, csr_src, N, TOT, nbuck);

    // gather + epilogue
    k_gather<<<(N + 3) / 4, 256, 0, stream>>>(csr_src, rowptr, hB, asrc, adst,
                                              bias, gamma, beta, out, N);
}